// Round 7
// baseline (2011.807 us; speedup 1.0000x reference)
//
#include <hip/hip_runtime.h>

// ---------------------------------------------------------------------------
// CycleS loss on MI355X (gfx950).
// Round 7: barrier-minimal 256x256 GEMM. Round 6 proved conflicts=0 but the
// 8-barrier/K-tile lockstep skeleton stalls ~60% of cycles. Now: 2 barriers
// per K-tile (write-protect + landed), counted vmcnt(8), whole-tile compute
// region left to the compiler's fine-grained lgkmcnt scheduling. Swizzled
// panels + XCD grid swizzle + fused aux kernels retained.
// ---------------------------------------------------------------------------

#define NN 4096
#define DD 1024
static constexpr float SCALE_F = 83.17766166719343f; // ln(4096)/0.1

typedef short  s16x8 __attribute__((ext_vector_type(8)));
typedef float  f32x4 __attribute__((ext_vector_type(4)));

__device__ __forceinline__ float bflo(unsigned w) { return __uint_as_float(w << 16); }
__device__ __forceinline__ float bfhi(unsigned w) { return __uint_as_float(w & 0xffff0000u); }
__device__ __forceinline__ unsigned short f2bf(float f) {
  unsigned u = __float_as_uint(f);
  u += 0x7fffu + ((u >> 16) & 1u);
  return (unsigned short)(u >> 16);
}
__device__ __forceinline__ unsigned pack2(float a, float b) {
  return (unsigned)f2bf(a) | ((unsigned)f2bf(b) << 16);
}
__device__ __forceinline__ void amaxf(float* a, float v) {
  atomicMax((int*)a, __float_as_int(v)); // valid: all values >= 0
}
__device__ __forceinline__ void gl_lds16(const void* g, void* l) {
  __builtin_amdgcn_global_load_lds(
      (const __attribute__((address_space(1))) void*)g,
      (__attribute__((address_space(3))) void*)l, 16, 0, 0);
}

// ---------------------------------------------------------------------------
__global__ __launch_bounds__(256) void cyc_zero(float* p, int n) {
  int i = blockIdx.x * 256 + threadIdx.x;
  if (i < n) p[i] = 0.f;
}

// row-normalize fp32 -> bf16. one block per row, 256 threads * float4
__global__ __launch_bounds__(256) void cyc_norm(const float* __restrict__ in,
                                                unsigned short* __restrict__ out) {
  int row = blockIdx.x, t = threadIdx.x;
  float4 v = *(const float4*)(in + (size_t)row * DD + t * 4);
  float ss = v.x * v.x + v.y * v.y + v.z * v.z + v.w * v.w;
  for (int o = 32; o > 0; o >>= 1) ss += __shfl_down(ss, o);
  __shared__ float red[4];
  if ((t & 63) == 0) red[t >> 6] = ss;
  __syncthreads();
  float tot = red[0] + red[1] + red[2] + red[3];
  float sc = 1.f / fmaxf(sqrtf(tot), 1e-12f);
  uint2 o;
  o.x = pack2(v.x * sc, v.y * sc);
  o.y = pack2(v.z * sc, v.w * sc);
  *(uint2*)(out + (size_t)row * DD + t * 4) = o;
}

// ---------------------------------------------------------------------------
// NT GEMM: C[4096][4096] = A[4096][KT] @ B[4096][KT]^T   (bf16 in, fp32 acc)
// 256x256 tile, BK=64, 8 waves (2Mx4N), 512 threads. LDS panels [256][32]
// bf16 with XOR slot swizzle (slot ^= (row>>1)&3) — 0 bank conflicts (r6).
// Sync: 2 barriers + 1 counted vmcnt(8) per K-tile; compute region is
// compiler-scheduled (fine lgkmcnt interleave).
// REDUCE: skip C write; emit diag + offdiag row/col max (atomicMax).
template <int KT, bool REDUCE>
__global__ __launch_bounds__(512, 2) void cyc_gemm(
    const unsigned short* __restrict__ A, const unsigned short* __restrict__ B,
    unsigned short* __restrict__ C, float* __restrict__ rowmax,
    float* __restrict__ colmax, float* __restrict__ diag) {
  __shared__ alignas(16) unsigned short LA[2][2][256][32]; // 64 KB
  __shared__ alignas(16) unsigned short LB[2][2][256][32]; // 64 KB
  __shared__ float redrow[256];
  __shared__ float redcol[256];

  constexpr int NT = KT / 64;
  const int orig = blockIdx.x;
  const int bid = ((orig & 7) << 5) | (orig >> 3); // XCD swizzle (256 % 8 == 0)
  const int bm = bid >> 4, bn = bid & 15;
  const int m0 = bm << 8, n0 = bn << 8;
  const int tid = threadIdx.x;
  const int l = tid & 63, w = tid >> 6;
  const int wm = w >> 2, wn = w & 3;
  const int fr = l & 15, fq = l >> 4;
  const int ar = wm * 128 + fr; // + mh*64 + j*16
  const int br = wn * 64 + fr;  // + n*16
  // swizzled read col (elements), per-lane constant: (fq ^ ((row>>1)&3))*8
  const int rc = ((fq ^ ((fr >> 1) & 3)) << 3);
  // staging geometry: per call each thread moves 2 chunks (rows r, r+128)
  const int st_r0 = tid >> 2;            // 0..127
  const int st_r1 = st_r0 + 128;
  const int st_dc = (tid & 3) << 3;      // LDS dest col (linear!)
  const int st_sc = (((tid & 3) ^ ((st_r0 >> 1) & 3)) << 3); // global src col
  // note: ((st_r1>>1)&3) == ((st_r0>>1)&3) since 128>>1 = 64 == 0 (mod 4)

  f32x4 acc[8][4];
#pragma unroll
  for (int m = 0; m < 8; ++m)
#pragma unroll
    for (int n = 0; n < 4; ++n) acc[m][n] = (f32x4){0.f, 0.f, 0.f, 0.f};
  s16x8 af[4], bfv[4];

#define STAGE_A(buf, kk, kbase)                                              \
  {                                                                          \
    gl_lds16(A + (size_t)(m0 + st_r0) * KT + (kbase) + (kk) * 32 + st_sc,    \
             &LA[buf][kk][st_r0][st_dc]);                                    \
    gl_lds16(A + (size_t)(m0 + st_r1) * KT + (kbase) + (kk) * 32 + st_sc,    \
             &LA[buf][kk][st_r1][st_dc]);                                    \
  }
#define STAGE_B(buf, kk, kbase)                                              \
  {                                                                          \
    gl_lds16(B + (size_t)(n0 + st_r0) * KT + (kbase) + (kk) * 32 + st_sc,    \
             &LB[buf][kk][st_r0][st_dc]);                                    \
    gl_lds16(B + (size_t)(n0 + st_r1) * KT + (kbase) + (kk) * 32 + st_sc,    \
             &LB[buf][kk][st_r1][st_dc]);                                    \
  }
#define STAGE_ALL(buf, kbase)                                                \
  STAGE_A(buf, 0, kbase) STAGE_B(buf, 0, kbase)                              \
  STAGE_A(buf, 1, kbase) STAGE_B(buf, 1, kbase)
#define LOAD_A4(buf, kk, mh)                                                 \
  _Pragma("unroll") for (int j = 0; j < 4; ++j) af[j] =                      \
      *(const s16x8*)&LA[buf][kk][ar + (mh)*64 + j * 16][rc];
#define LOAD_B4(buf, kk)                                                     \
  _Pragma("unroll") for (int n = 0; n < 4; ++n) bfv[n] =                     \
      *(const s16x8*)&LB[buf][kk][br + n * 16][rc];
#define MFMA_Q(mh)                                                           \
  _Pragma("unroll") for (int n = 0; n < 4; ++n)                              \
  _Pragma("unroll") for (int m = 0; m < 4; ++m)                              \
      acc[(mh)*4 + m][n] = __builtin_amdgcn_mfma_f32_16x16x32_bf16(          \
          af[m], bfv[n], acc[(mh)*4 + m][n], 0, 0, 0);
#define BAR() __builtin_amdgcn_s_barrier()
#define SCHED0() __builtin_amdgcn_sched_barrier(0)
#define VM(n) asm volatile("s_waitcnt vmcnt(" #n ")" ::: "memory")
  // whole-tile compute region: compiler inserts fine-grained lgkmcnt and
  // interleaves ds_read/MFMA; setprio hints the CU scheduler per cluster.
#define COMPUTE_TILE(p)                                                      \
  {                                                                          \
    LOAD_A4(p, 0, 0) LOAD_B4(p, 0)                                           \
    __builtin_amdgcn_s_setprio(1);                                           \
    MFMA_Q(0)                                                                \
    __builtin_amdgcn_s_setprio(0);                                           \
    LOAD_A4(p, 0, 1)                                                         \
    __builtin_amdgcn_s_setprio(1);                                           \
    MFMA_Q(1)                                                                \
    __builtin_amdgcn_s_setprio(0);                                           \
    LOAD_A4(p, 1, 0) LOAD_B4(p, 1)                                           \
    __builtin_amdgcn_s_setprio(1);                                           \
    MFMA_Q(0)                                                                \
    __builtin_amdgcn_s_setprio(0);                                           \
    LOAD_A4(p, 1, 1)                                                         \
    __builtin_amdgcn_s_setprio(1);                                           \
    MFMA_Q(1)                                                                \
    __builtin_amdgcn_s_setprio(0);                                           \
  }

  // prologue: stage tile 0 (8 loads in flight)
  STAGE_ALL(0, 0)

#pragma unroll 1
  for (int ti = 0; ti < NT - 1; ++ti) {
    const int p = ti & 1;
    // barrier 1: everyone finished READING buf p^1 (tile ti-1) -> safe to
    // overwrite it with tile ti+1's panels.
    BAR();
    SCHED0();
    STAGE_ALL(p ^ 1, (ti + 1) * 64)   // 8 loads; total outstanding now 16
    VM(8);                            // tile ti's 8 loads have landed
    // barrier 2: all waves' VM(8) passed -> buf p complete for everyone.
    BAR();
    SCHED0();
    COMPUTE_TILE(p)
  }
  // final tile: no staging; drain all loads
  {
    const int p = (NT - 1) & 1;
    BAR();
    SCHED0();
    VM(0);
    BAR();
    SCHED0();
    COMPUTE_TILE(p)
  }

  if constexpr (!REDUCE) {
#pragma unroll
    for (int m = 0; m < 8; ++m)
#pragma unroll
      for (int n = 0; n < 4; ++n)
#pragma unroll
        for (int j = 0; j < 4; ++j) {
          int gr = m0 + wm * 128 + m * 16 + fq * 4 + j;
          int gc = n0 + wn * 64 + n * 16 + fr;
          C[(size_t)gr * NN + gc] = f2bf(acc[m][n][j]);
        }
  } else {
    __syncthreads(); // reuse of LDS red arrays after K-loop
    if (tid < 256) redrow[tid] = 0.f;
    else redcol[tid - 256] = 0.f;
    __syncthreads();
    // row maxes (offdiag; diag captured exactly once grid-wide)
#pragma unroll
    for (int m = 0; m < 8; ++m)
#pragma unroll
      for (int j = 0; j < 4; ++j) {
        int lr = wm * 128 + m * 16 + fq * 4 + j;
        int prow = m0 + lr;
        float rm = 0.f;
#pragma unroll
        for (int n = 0; n < 4; ++n) {
          int q = n0 + wn * 64 + n * 16 + fr;
          float v = acc[m][n][j];
          if (prow == q) { diag[prow] = v; v = 0.f; }
          rm = fmaxf(rm, v);
        }
        rm = fmaxf(rm, __shfl_xor(rm, 1));
        rm = fmaxf(rm, __shfl_xor(rm, 2));
        rm = fmaxf(rm, __shfl_xor(rm, 4));
        rm = fmaxf(rm, __shfl_xor(rm, 8));
        if (fr == 0) amaxf(&redrow[lr], rm);
      }
    // col maxes
#pragma unroll
    for (int n = 0; n < 4; ++n) {
      int lc = wn * 64 + n * 16 + fr;
      int q = n0 + lc;
      float cm = 0.f;
#pragma unroll
      for (int m = 0; m < 8; ++m)
#pragma unroll
        for (int j = 0; j < 4; ++j) {
          int prow = m0 + wm * 128 + m * 16 + fq * 4 + j;
          float v = acc[m][n][j];
          if (prow == q) v = 0.f;
          cm = fmaxf(cm, v);
        }
      cm = fmaxf(cm, __shfl_xor(cm, 16));
      cm = fmaxf(cm, __shfl_xor(cm, 32));
      if (fq == 0) amaxf(&redcol[lc], cm);
    }
    __syncthreads();
    if (tid < 256) amaxf(&rowmax[m0 + tid], redrow[tid]);
    else amaxf(&colmax[n0 + (tid - 256)], redcol[tid - 256]);
  }
#undef STAGE_A
#undef STAGE_B
#undef STAGE_ALL
#undef LOAD_A4
#undef LOAD_B4
#undef MFMA_Q
#undef BAR
#undef SCHED0
#undef VM
#undef COMPUTE_TILE
}

// ---------------------------------------------------------------------------
// LDS-tiled transpose, bf16 4096x4096
__global__ __launch_bounds__(256) void cyc_trans(const unsigned short* __restrict__ in,
                                                 unsigned short* __restrict__ out) {
  __shared__ alignas(16) unsigned short tile[128][136];
  int bx = blockIdx.x & 31, by = blockIdx.x >> 5;
  int r0 = by << 7, c0 = bx << 7;
  int t = threadIdx.x;
#pragma unroll
  for (int i = 0; i < 8; ++i) {
    int lin = i * 256 + t;
    int r = lin >> 4;
    int c8 = (lin & 15) << 3;
    *(uint4*)(&tile[r][c8]) = *(const uint4*)(in + (size_t)(r0 + r) * NN + c0 + c8);
  }
  __syncthreads();
#pragma unroll
  for (int i = 0; i < 8; ++i) {
    int lin = i * 256 + t;
    int c = lin >> 4;
    int r8 = (lin & 15) << 3;
    unsigned short v[8];
#pragma unroll
    for (int j = 0; j < 8; ++j) v[j] = tile[r8 + j][c];
    uint4 o;
    o.x = (unsigned)v[0] | ((unsigned)v[1] << 16);
    o.y = (unsigned)v[2] | ((unsigned)v[3] << 16);
    o.z = (unsigned)v[4] | ((unsigned)v[5] << 16);
    o.w = (unsigned)v[6] | ((unsigned)v[7] << 16);
    *(uint4*)(out + (size_t)(c0 + c) * NN + r0 + r8) = o;
  }
}

// ---------------------------------------------------------------------------
// fused row+col sums of exp(scale*X): grid (2,256), 2048 cols x 16 rows/block
__global__ __launch_bounds__(256) void cyc_sums(const unsigned short* __restrict__ X,
                                                float* __restrict__ rs,
                                                float* __restrict__ cs) {
  int t = threadIdx.x;
  int c0 = blockIdx.x * 2048 + t * 8;
  int r0 = blockIdx.y * 16;
  float a[8];
#pragma unroll
  for (int j = 0; j < 8; ++j) a[j] = 0.f;
  for (int r = 0; r < 16; ++r) {
    uint4 u = *(const uint4*)(X + (size_t)(r0 + r) * NN + c0);
    float e0 = __expf(SCALE_F * bflo(u.x)), e1 = __expf(SCALE_F * bfhi(u.x));
    float e2 = __expf(SCALE_F * bflo(u.y)), e3 = __expf(SCALE_F * bfhi(u.y));
    float e4 = __expf(SCALE_F * bflo(u.z)), e5 = __expf(SCALE_F * bfhi(u.z));
    float e6 = __expf(SCALE_F * bflo(u.w)), e7 = __expf(SCALE_F * bfhi(u.w));
    a[0] += e0; a[1] += e1; a[2] += e2; a[3] += e3;
    a[4] += e4; a[5] += e5; a[6] += e6; a[7] += e7;
    float p = ((e0 + e1) + (e2 + e3)) + ((e4 + e5) + (e6 + e7));
    for (int o = 32; o > 0; o >>= 1) p += __shfl_xor(p, o);
    if ((t & 63) == 0) atomicAdd(&rs[r0 + r], p);
  }
#pragma unroll
  for (int j = 0; j < 8; ++j) atomicAdd(&cs[c0 + j], a[j]);
}

// A = rowsoftmax, Bc = colsoftmax (bf16); reciprocals computed inline
__global__ __launch_bounds__(256) void cyc_abgen(const unsigned short* __restrict__ X,
                                                 const float* __restrict__ rsum,
                                                 const float* __restrict__ csum,
                                                 unsigned short* __restrict__ A,
                                                 unsigned short* __restrict__ B) {
  size_t idx = (size_t)blockIdx.x * 256 + threadIdx.x;
  int row = (int)(idx >> 9);
  int c0 = ((int)idx & 511) << 3;
  size_t off = ((size_t)row << 12) + c0;
  uint4 u = *(const uint4*)(X + off);
  float ri = 1.f / rsum[row];
  float4 cs0 = *(const float4*)(csum + c0);
  float4 cs1 = *(const float4*)(csum + c0 + 4);
  float ci0 = 1.f / cs0.x, ci1 = 1.f / cs0.y, ci2 = 1.f / cs0.z, ci3 = 1.f / cs0.w;
  float ci4 = 1.f / cs1.x, ci5 = 1.f / cs1.y, ci6 = 1.f / cs1.z, ci7 = 1.f / cs1.w;
  float e0 = __expf(SCALE_F * bflo(u.x)), e1 = __expf(SCALE_F * bfhi(u.x));
  float e2 = __expf(SCALE_F * bflo(u.y)), e3 = __expf(SCALE_F * bfhi(u.y));
  float e4 = __expf(SCALE_F * bflo(u.z)), e5 = __expf(SCALE_F * bfhi(u.z));
  float e6 = __expf(SCALE_F * bflo(u.w)), e7 = __expf(SCALE_F * bfhi(u.w));
  uint4 oa, ob;
  oa.x = pack2(e0 * ri, e1 * ri); oa.y = pack2(e2 * ri, e3 * ri);
  oa.z = pack2(e4 * ri, e5 * ri); oa.w = pack2(e6 * ri, e7 * ri);
  ob.x = pack2(e0 * ci0, e1 * ci1); ob.y = pack2(e2 * ci2, e3 * ci3);
  ob.z = pack2(e4 * ci4, e5 * ci5); ob.w = pack2(e6 * ci6, e7 * ci7);
  *(uint4*)(A + off) = oa;
  *(uint4*)(B + off) = ob;
}

// partial loss: grid 24 (6 terms x 4 quarters), 256 thr; atomicAdd into accum
__global__ __launch_bounds__(256) void cyc_lossA(const float* __restrict__ arr,
                                                 float* __restrict__ accum) {
  int term = blockIdx.x >> 2, quarter = blockIdx.x & 3;
  int t = threadIdx.x;
  const float* base = arr + (size_t)term * 5 * NN;
  const float* rm = base + 2 * NN;
  const float* cm = base + 3 * NN;
  const float* dg = base + 4 * NN;
  float s = 0.f;
  for (int i = quarter * 1024 + t; i < (quarter + 1) * 1024; i += 256) {
    float d = dg[i];
    s += fmaxf(rm[i] + 0.5f - d, 0.f) + fmaxf(cm[i] + 0.5f - d, 0.f);
  }
  for (int o = 32; o > 0; o >>= 1) s += __shfl_xor(s, o);
  __shared__ float red[4];
  if ((t & 63) == 0) red[t >> 6] = s;
  __syncthreads();
  if (t == 0) atomicAdd(accum, red[0] + red[1] + red[2] + red[3]);
}

__global__ void cyc_lossB(const float* __restrict__ accum, float* __restrict__ out) {
  if (threadIdx.x == 0) out[0] = accum[0] * (1.f / (2.f * NN * 3.f));
}

// ---------------------------------------------------------------------------
static void process_term(const unsigned short* X, int term, unsigned short* Abuf,
                         unsigned short* Bbuf, float* arr, hipStream_t s) {
  float* base = arr + (size_t)term * 5 * NN;
  float* rs = base;
  float* cs = base + NN;
  float* rmax = base + 2 * NN;
  float* cmax = base + 3 * NN;
  float* dg = base + 4 * NN;
  cyc_sums<<<dim3(2, 256), 256, 0, s>>>(X, rs, cs);
  cyc_abgen<<<8192, 256, 0, s>>>(X, rs, cs, Abuf, Bbuf);
  cyc_gemm<NN, true><<<256, 512, 0, s>>>(Abuf, Bbuf, nullptr, rmax, cmax, dg);
}

extern "C" void kernel_launch(void* const* d_in, const int* in_sizes, int n_in,
                              void* d_out, int out_size, void* d_ws, size_t ws_size,
                              hipStream_t stream) {
  (void)in_sizes; (void)n_in; (void)out_size; (void)ws_size;
  const float* f0 = (const float*)d_in[0];
  const float* f1 = (const float*)d_in[1];
  const float* f2 = (const float*)d_in[2];
  char* ws = (char*)d_ws;

  const size_t NF_ELEMS = (size_t)NN * DD;     // 4M shorts = 8 MB
  const size_t S_ELEMS = (size_t)NN * NN;      // 16M shorts = 32 MB
  unsigned short* NF0 = (unsigned short*)ws;
  unsigned short* NF1 = NF0 + NF_ELEMS;
  unsigned short* NF2 = NF1 + NF_ELEMS;
  unsigned short* SA = NF2 + NF_ELEMS; // S01
  unsigned short* SB = SA + S_ELEMS;   // S02
  unsigned short* SC = SB + S_ELEMS;   // S12
  unsigned short* TB = SC + S_ELEMS;   // scratch matrix
  unsigned short* AB = TB + S_ELEMS;   // A (rowsoftmax)
  unsigned short* BB = AB + S_ELEMS;   // Bc (colsoftmax)
  float* arr = (float*)(BB + S_ELEMS); // [6][5][4096] fp32 + accum
  float* accum = arr + 6 * 5 * NN;
  float* out = (float*)d_out;

  cyc_zero<<<(6 * 5 * NN + 256 + 255) / 256, 256, 0, stream>>>(arr, 6 * 5 * NN + 256);
  cyc_norm<<<NN, 256, 0, stream>>>(f0, NF0);
  cyc_norm<<<NN, 256, 0, stream>>>(f1, NF1);
  cyc_norm<<<NN, 256, 0, stream>>>(f2, NF2);

  // pair similarity matrices
  cyc_gemm<DD, false><<<256, 512, 0, stream>>>(NF0, NF1, SA, nullptr, nullptr, nullptr);
  cyc_gemm<DD, false><<<256, 512, 0, stream>>>(NF0, NF2, SB, nullptr, nullptr, nullptr);
  cyc_gemm<DD, false><<<256, 512, 0, stream>>>(NF1, NF2, SC, nullptr, nullptr, nullptr);

  // pair terms
  process_term(SA, 0, AB, BB, arr, stream);
  process_term(SB, 1, AB, BB, arr, stream);
  process_term(SC, 2, AB, BB, arr, stream);

  // T1 = S02 @ S12^T = NT(SB, SC)
  cyc_gemm<NN, false><<<256, 512, 0, stream>>>(SB, SC, TB, nullptr, nullptr, nullptr);
  process_term(TB, 3, AB, BB, arr, stream);

  // T2 = S01 @ S12 = NT(SA, S12^T): transpose SC -> TB, output into SC slot
  cyc_trans<<<1024, 256, 0, stream>>>(SC, TB);
  cyc_gemm<NN, false><<<256, 512, 0, stream>>>(SA, TB, SC, nullptr, nullptr, nullptr);
  process_term(SC, 4, AB, BB, arr, stream);

  // T3 = S01^T @ S02 = NT(S01^T, S02^T): S10 -> TB, S20 -> AB, out into SA slot
  cyc_trans<<<1024, 256, 0, stream>>>(SA, TB);
  cyc_trans<<<1024, 256, 0, stream>>>(SB, AB);
  cyc_gemm<NN, false><<<256, 512, 0, stream>>>(TB, AB, SA, nullptr, nullptr, nullptr);
  process_term(SA, 5, AB, BB, arr, stream);

  cyc_lossA<<<24, 256, 0, stream>>>(arr, accum);
  cyc_lossB<<<1, 64, 0, stream>>>(accum, out);
}

// Round 8
// 1431.873 us; speedup vs baseline: 1.4050x; 1.4050x over previous
//
#include <hip/hip_runtime.h>

// ---------------------------------------------------------------------------
// CycleS loss on MI355X (gfx950).
// Round 8: round-6 phase skeleton (proven: 0 conflicts, correct) + m201-depth
// pipeline: 2-K-tile iteration, 8 phases, ONE 16KB panel staged per phase,
// VM(8) at even phases (awaited loads are 6 phases old -> non-stalling),
// 12-load steady in-flight window. Epilogue of C-writing GEMMs now emits
// row/col exp-sums (cyc_sums kernels eliminated).
//
// Stage ledger (iteration i, t=2i, buf parity: even tile->0, odd->1):
//  ph1 read[0][kk0]mh0  stage (t+1).A-kk1 -> LA[1][1]
//  ph2 read[0][kk0]mh1  stage (t+1).B-kk1 -> LB[1][1]  VM(8): (t).kk1 landed
//  ph3 read[0][kk1]mh0  stage (t+2).A-kk0 -> LA[0][0]   (slot last read ph1-2)
//  ph4 read[0][kk1]mh1  stage (t+2).B-kk0 -> LB[0][0]  VM(8): (t+1).kk0 landed
//  ph5 read[1][kk0]mh0  stage (t+2).A-kk1 -> LA[0][1]   (slot last read ph3-4)
//  ph6 read[1][kk0]mh1  stage (t+2).B-kk1 -> LB[0][1]  VM(8): (t+1).kk1 landed
//  ph7 read[1][kk1]mh0  stage (t+3).A-kk0 -> LA[1][0]   (slot last read ph5-6)
//  ph8 read[1][kk1]mh1  stage (t+3).B-kk0 -> LB[1][0]  VM(8): (t+2).kk0 landed
// ---------------------------------------------------------------------------

#define NN 4096
#define DD 1024
static constexpr float SCALE_F = 83.17766166719343f; // ln(4096)/0.1

typedef short  s16x8 __attribute__((ext_vector_type(8)));
typedef float  f32x4 __attribute__((ext_vector_type(4)));

__device__ __forceinline__ float bflo(unsigned w) { return __uint_as_float(w << 16); }
__device__ __forceinline__ float bfhi(unsigned w) { return __uint_as_float(w & 0xffff0000u); }
__device__ __forceinline__ unsigned short f2bf(float f) {
  unsigned u = __float_as_uint(f);
  u += 0x7fffu + ((u >> 16) & 1u);
  return (unsigned short)(u >> 16);
}
__device__ __forceinline__ unsigned pack2(float a, float b) {
  return (unsigned)f2bf(a) | ((unsigned)f2bf(b) << 16);
}
__device__ __forceinline__ void amaxf(float* a, float v) {
  atomicMax((int*)a, __float_as_int(v)); // valid: all values >= 0
}
__device__ __forceinline__ void gl_lds16(const void* g, void* l) {
  __builtin_amdgcn_global_load_lds(
      (const __attribute__((address_space(1))) void*)g,
      (__attribute__((address_space(3))) void*)l, 16, 0, 0);
}

// ---------------------------------------------------------------------------
__global__ __launch_bounds__(256) void cyc_zero(float* p, int n) {
  int i = blockIdx.x * 256 + threadIdx.x;
  if (i < n) p[i] = 0.f;
}

// row-normalize fp32 -> bf16. one block per row, 256 threads * float4
__global__ __launch_bounds__(256) void cyc_norm(const float* __restrict__ in,
                                                unsigned short* __restrict__ out) {
  int row = blockIdx.x, t = threadIdx.x;
  float4 v = *(const float4*)(in + (size_t)row * DD + t * 4);
  float ss = v.x * v.x + v.y * v.y + v.z * v.z + v.w * v.w;
  for (int o = 32; o > 0; o >>= 1) ss += __shfl_down(ss, o);
  __shared__ float red[4];
  if ((t & 63) == 0) red[t >> 6] = ss;
  __syncthreads();
  float tot = red[0] + red[1] + red[2] + red[3];
  float sc = 1.f / fmaxf(sqrtf(tot), 1e-12f);
  uint2 o;
  o.x = pack2(v.x * sc, v.y * sc);
  o.y = pack2(v.z * sc, v.w * sc);
  *(uint2*)(out + (size_t)row * DD + t * 4) = o;
}

// ---------------------------------------------------------------------------
// NT GEMM: C[4096][4096] = A[4096][KT] @ B[4096][KT]^T   (bf16 in, fp32 acc)
// 256x256 tile, BK=64, 8 waves (2Mx4N), 512 threads. LDS panels [256][32]
// bf16, XOR slot swizzle (0 conflicts, r6-verified).
// REDUCE=false: write C + emit row/col sums of exp(SCALE*bf16(C)).
// REDUCE=true: no C write; emit diag + offdiag row/col max.
template <int KT, bool REDUCE>
__global__ __launch_bounds__(512, 2) void cyc_gemm(
    const unsigned short* __restrict__ A, const unsigned short* __restrict__ B,
    unsigned short* __restrict__ C, float* __restrict__ rout,
    float* __restrict__ cout_, float* __restrict__ diag) {
  __shared__ alignas(16) unsigned short LA[2][2][256][32]; // 64 KB
  __shared__ alignas(16) unsigned short LB[2][2][256][32]; // 64 KB
  __shared__ float redrow[256];
  __shared__ float redcol[256];

  constexpr int NT = KT / 64;
  constexpr int NIT = NT / 2;
  static_assert(NIT >= 2, "need >= 4 K-tiles");
  const int orig = blockIdx.x;
  const int bid = ((orig & 7) << 5) | (orig >> 3); // XCD swizzle (256 % 8 == 0)
  const int bm = bid >> 4, bn = bid & 15;
  const int m0 = bm << 8, n0 = bn << 8;
  const int tid = threadIdx.x;
  const int l = tid & 63, w = tid >> 6;
  const int wm = w >> 2, wn = w & 3;
  const int fr = l & 15, fq = l >> 4;
  const int ar = wm * 128 + fr; // + mh*64 + j*16
  const int br = wn * 64 + fr;  // + n*16
  // swizzled read col (elements), per-lane constant: (fq ^ ((row>>1)&3))*8
  const int rc = ((fq ^ ((fr >> 1) & 3)) << 3);
  // staging geometry: per call each thread moves 2 chunks (rows r, r+128)
  const int st_r0 = tid >> 2;            // 0..127
  const int st_r1 = st_r0 + 128;
  const int st_dc = (tid & 3) << 3;      // LDS dest col (linear!)
  const int st_sc = (((tid & 3) ^ ((st_r0 >> 1) & 3)) << 3); // global src col

  f32x4 acc[8][4];
#pragma unroll
  for (int m = 0; m < 8; ++m)
#pragma unroll
    for (int n = 0; n < 4; ++n) acc[m][n] = (f32x4){0.f, 0.f, 0.f, 0.f};
  s16x8 af[4], bfv[4];

#define STAGE_A(buf, kk, kbase)                                              \
  {                                                                          \
    gl_lds16(A + (size_t)(m0 + st_r0) * KT + (kbase) + (kk) * 32 + st_sc,    \
             &LA[buf][kk][st_r0][st_dc]);                                    \
    gl_lds16(A + (size_t)(m0 + st_r1) * KT + (kbase) + (kk) * 32 + st_sc,    \
             &LA[buf][kk][st_r1][st_dc]);                                    \
  }
#define STAGE_B(buf, kk, kbase)                                              \
  {                                                                          \
    gl_lds16(B + (size_t)(n0 + st_r0) * KT + (kbase) + (kk) * 32 + st_sc,    \
             &LB[buf][kk][st_r0][st_dc]);                                    \
    gl_lds16(B + (size_t)(n0 + st_r1) * KT + (kbase) + (kk) * 32 + st_sc,    \
             &LB[buf][kk][st_r1][st_dc]);                                    \
  }
#define LOAD_A4(buf, kk, mh)                                                 \
  _Pragma("unroll") for (int j = 0; j < 4; ++j) af[j] =                      \
      *(const s16x8*)&LA[buf][kk][ar + (mh)*64 + j * 16][rc];
#define LOAD_B4(buf, kk)                                                     \
  _Pragma("unroll") for (int n = 0; n < 4; ++n) bfv[n] =                     \
      *(const s16x8*)&LB[buf][kk][br + n * 16][rc];
#define MFMA_Q(mh)                                                           \
  _Pragma("unroll") for (int n = 0; n < 4; ++n)                              \
  _Pragma("unroll") for (int m = 0; m < 4; ++m)                              \
      acc[(mh)*4 + m][n] = __builtin_amdgcn_mfma_f32_16x16x32_bf16(          \
          af[m], bfv[n], acc[(mh)*4 + m][n], 0, 0, 0);
#define BAR() __builtin_amdgcn_s_barrier()
#define SCHED0() __builtin_amdgcn_sched_barrier(0)
#define WAIT_LGKM() asm volatile("s_waitcnt lgkmcnt(0)" ::: "memory")
#define LGKM4() asm volatile("s_waitcnt lgkmcnt(4)" ::: "memory")
#define VM(n) asm volatile("s_waitcnt vmcnt(" #n ")" ::: "memory")
  // mh0 phase: 8 ds_reads (A half + B) + optional stage; partial lgkm drain
#define PH_A(pbuf, kk, stage_stmt, vmstmt)                                   \
  {                                                                          \
    LOAD_A4(pbuf, kk, 0) LOAD_B4(pbuf, kk)                                   \
    stage_stmt                                                               \
    LGKM4();                                                                 \
    BAR();                                                                   \
    WAIT_LGKM();                                                             \
    SCHED0();                                                                \
    __builtin_amdgcn_s_setprio(1);                                           \
    MFMA_Q(0)                                                                \
    __builtin_amdgcn_s_setprio(0);                                           \
    vmstmt                                                                   \
    BAR();                                                                   \
  }
  // mh1 phase: 4 ds_reads (bfv reused)
#define PH_B(pbuf, kk, stage_stmt, vmstmt)                                   \
  {                                                                          \
    LOAD_A4(pbuf, kk, 1)                                                     \
    stage_stmt                                                               \
    BAR();                                                                   \
    WAIT_LGKM();                                                             \
    SCHED0();                                                                \
    __builtin_amdgcn_s_setprio(1);                                           \
    MFMA_Q(1)                                                                \
    __builtin_amdgcn_s_setprio(0);                                           \
    vmstmt                                                                   \
    BAR();                                                                   \
  }

  // prologue: tile0 fully (u1..u4) + tile1 kk0 (u1,u2) = 12 loads
  STAGE_A(0, 0, 0) STAGE_B(0, 0, 0) STAGE_A(0, 1, 0) STAGE_B(0, 1, 0)
  STAGE_A(1, 0, 64) STAGE_B(1, 0, 64)
  VM(8); // oldest 4 = tile0 kk0 landed
  BAR();

#pragma unroll 1
  for (int i = 0; i < NIT - 1; ++i) {
    const int t = 2 * i;
    const int k1 = (t + 1) * 64, k2 = (t + 2) * 64, k3 = (t + 3) * 64;
    PH_A(0, 0, STAGE_A(1, 1, k1), )          // ph1
    PH_B(0, 0, STAGE_B(1, 1, k1), VM(8);)    // ph2: (t).kk1 landed
    PH_A(0, 1, STAGE_A(0, 0, k2), )          // ph3
    PH_B(0, 1, STAGE_B(0, 0, k2), VM(8);)    // ph4: (t+1).kk0 landed
    PH_A(1, 0, STAGE_A(0, 1, k2), )          // ph5
    PH_B(1, 0, STAGE_B(0, 1, k2), VM(8);)    // ph6: (t+1).kk1 landed
    PH_A(1, 1, STAGE_A(1, 0, k3), )          // ph7
    PH_B(1, 1, STAGE_B(1, 0, k3), VM(8);)    // ph8: (t+2).kk0 landed
  }
  // final iteration (t = NT-2): only (NT-1).kk1 remains to stage
  {
    const int k1 = (NT - 1) * 64;
    PH_A(0, 0, STAGE_A(1, 1, k1), )
    PH_B(0, 0, STAGE_B(1, 1, k1), VM(8);)    // (NT-2).kk1 landed
    PH_A(0, 1, , )
    PH_B(0, 1, , VM(4);)                     // (NT-1).kk0 landed
    PH_A(1, 0, , )
    PH_B(1, 0, , VM(0);)                     // (NT-1).kk1 landed
    PH_A(1, 1, , )
    PH_B(1, 1, , )
  }

  if constexpr (!REDUCE) {
    // write C (bf16) + row/col sums of exp(SCALE * bf16val)
    if (tid < 256) redrow[tid] = 0.f;
    else redcol[tid - 256] = 0.f;
    __syncthreads();
    float colpart[4] = {0.f, 0.f, 0.f, 0.f};
#pragma unroll
    for (int m = 0; m < 8; ++m)
#pragma unroll
      for (int j = 0; j < 4; ++j) {
        int lr = wm * 128 + m * 16 + fq * 4 + j;
        int gr = m0 + lr;
        float rowpart = 0.f;
#pragma unroll
        for (int n = 0; n < 4; ++n) {
          unsigned short us = f2bf(acc[m][n][j]);
          C[(size_t)gr * NN + (n0 + wn * 64 + n * 16 + fr)] = us;
          float e = __expf(SCALE_F * __uint_as_float((unsigned)us << 16));
          rowpart += e;
          colpart[n] += e;
        }
        rowpart += __shfl_xor(rowpart, 1);
        rowpart += __shfl_xor(rowpart, 2);
        rowpart += __shfl_xor(rowpart, 4);
        rowpart += __shfl_xor(rowpart, 8);
        if (fr == 0) atomicAdd(&redrow[lr], rowpart);
      }
#pragma unroll
    for (int n = 0; n < 4; ++n) {
      float cp = colpart[n];
      cp += __shfl_xor(cp, 16);
      cp += __shfl_xor(cp, 32);
      if (fq == 0) atomicAdd(&redcol[wn * 64 + n * 16 + fr], cp);
    }
    __syncthreads();
    if (tid < 256) atomicAdd(&rout[m0 + tid], redrow[tid]);
    else atomicAdd(&cout_[n0 + (tid - 256)], redcol[tid - 256]);
  } else {
    if (tid < 256) redrow[tid] = 0.f;
    else redcol[tid - 256] = 0.f;
    __syncthreads();
    // row maxes (offdiag; diag captured exactly once grid-wide)
#pragma unroll
    for (int m = 0; m < 8; ++m)
#pragma unroll
      for (int j = 0; j < 4; ++j) {
        int lr = wm * 128 + m * 16 + fq * 4 + j;
        int prow = m0 + lr;
        float rm = 0.f;
#pragma unroll
        for (int n = 0; n < 4; ++n) {
          int q = n0 + wn * 64 + n * 16 + fr;
          float v = acc[m][n][j];
          if (prow == q) { diag[prow] = v; v = 0.f; }
          rm = fmaxf(rm, v);
        }
        rm = fmaxf(rm, __shfl_xor(rm, 1));
        rm = fmaxf(rm, __shfl_xor(rm, 2));
        rm = fmaxf(rm, __shfl_xor(rm, 4));
        rm = fmaxf(rm, __shfl_xor(rm, 8));
        if (fr == 0) amaxf(&redrow[lr], rm);
      }
    // col maxes
#pragma unroll
    for (int n = 0; n < 4; ++n) {
      int lc = wn * 64 + n * 16 + fr;
      int q = n0 + lc;
      float cm = 0.f;
#pragma unroll
      for (int m = 0; m < 8; ++m)
#pragma unroll
        for (int j = 0; j < 4; ++j) {
          int prow = m0 + wm * 128 + m * 16 + fq * 4 + j;
          float v = acc[m][n][j];
          if (prow == q) v = 0.f;
          cm = fmaxf(cm, v);
        }
      cm = fmaxf(cm, __shfl_xor(cm, 16));
      cm = fmaxf(cm, __shfl_xor(cm, 32));
      if (fq == 0) amaxf(&redcol[lc], cm);
    }
    __syncthreads();
    if (tid < 256) amaxf(&rout[m0 + tid], redrow[tid]);
    else amaxf(&cout_[n0 + (tid - 256)], redcol[tid - 256]);
  }
#undef STAGE_A
#undef STAGE_B
#undef LOAD_A4
#undef LOAD_B4
#undef MFMA_Q
#undef BAR
#undef SCHED0
#undef WAIT_LGKM
#undef LGKM4
#undef VM
#undef PH_A
#undef PH_B
}

// ---------------------------------------------------------------------------
// LDS-tiled transpose, bf16 4096x4096
__global__ __launch_bounds__(256) void cyc_trans(const unsigned short* __restrict__ in,
                                                 unsigned short* __restrict__ out) {
  __shared__ alignas(16) unsigned short tile[128][136];
  int bx = blockIdx.x & 31, by = blockIdx.x >> 5;
  int r0 = by << 7, c0 = bx << 7;
  int t = threadIdx.x;
#pragma unroll
  for (int i = 0; i < 8; ++i) {
    int lin = i * 256 + t;
    int r = lin >> 4;
    int c8 = (lin & 15) << 3;
    *(uint4*)(&tile[r][c8]) = *(const uint4*)(in + (size_t)(r0 + r) * NN + c0 + c8);
  }
  __syncthreads();
#pragma unroll
  for (int i = 0; i < 8; ++i) {
    int lin = i * 256 + t;
    int c = lin >> 4;
    int r8 = (lin & 15) << 3;
    unsigned short v[8];
#pragma unroll
    for (int j = 0; j < 8; ++j) v[j] = tile[r8 + j][c];
    uint4 o;
    o.x = (unsigned)v[0] | ((unsigned)v[1] << 16);
    o.y = (unsigned)v[2] | ((unsigned)v[3] << 16);
    o.z = (unsigned)v[4] | ((unsigned)v[5] << 16);
    o.w = (unsigned)v[6] | ((unsigned)v[7] << 16);
    *(uint4*)(out + (size_t)(c0 + c) * NN + r0 + r8) = o;
  }
}

// ---------------------------------------------------------------------------
// A = rowsoftmax, Bc = colsoftmax (bf16); reciprocals computed inline
__global__ __launch_bounds__(256) void cyc_abgen(const unsigned short* __restrict__ X,
                                                 const float* __restrict__ rsum,
                                                 const float* __restrict__ csum,
                                                 unsigned short* __restrict__ A,
                                                 unsigned short* __restrict__ B) {
  size_t idx = (size_t)blockIdx.x * 256 + threadIdx.x;
  int row = (int)(idx >> 9);
  int c0 = ((int)idx & 511) << 3;
  size_t off = ((size_t)row << 12) + c0;
  uint4 u = *(const uint4*)(X + off);
  float ri = 1.f / rsum[row];
  float4 cs0 = *(const float4*)(csum + c0);
  float4 cs1 = *(const float4*)(csum + c0 + 4);
  float ci0 = 1.f / cs0.x, ci1 = 1.f / cs0.y, ci2 = 1.f / cs0.z, ci3 = 1.f / cs0.w;
  float ci4 = 1.f / cs1.x, ci5 = 1.f / cs1.y, ci6 = 1.f / cs1.z, ci7 = 1.f / cs1.w;
  float e0 = __expf(SCALE_F * bflo(u.x)), e1 = __expf(SCALE_F * bfhi(u.x));
  float e2 = __expf(SCALE_F * bflo(u.y)), e3 = __expf(SCALE_F * bfhi(u.y));
  float e4 = __expf(SCALE_F * bflo(u.z)), e5 = __expf(SCALE_F * bfhi(u.z));
  float e6 = __expf(SCALE_F * bflo(u.w)), e7 = __expf(SCALE_F * bfhi(u.w));
  uint4 oa, ob;
  oa.x = pack2(e0 * ri, e1 * ri); oa.y = pack2(e2 * ri, e3 * ri);
  oa.z = pack2(e4 * ri, e5 * ri); oa.w = pack2(e6 * ri, e7 * ri);
  ob.x = pack2(e0 * ci0, e1 * ci1); ob.y = pack2(e2 * ci2, e3 * ci3);
  ob.z = pack2(e4 * ci4, e5 * ci5); ob.w = pack2(e6 * ci6, e7 * ci7);
  *(uint4*)(A + off) = oa;
  *(uint4*)(B + off) = ob;
}

// partial loss: grid 24 (6 terms x 4 quarters), 256 thr; atomicAdd into accum
__global__ __launch_bounds__(256) void cyc_lossA(const float* __restrict__ arr,
                                                 float* __restrict__ accum) {
  int term = blockIdx.x >> 2, quarter = blockIdx.x & 3;
  int t = threadIdx.x;
  const float* base = arr + (size_t)term * 5 * NN;
  const float* rm = base + 2 * NN;
  const float* cm = base + 3 * NN;
  const float* dg = base + 4 * NN;
  float s = 0.f;
  for (int i = quarter * 1024 + t; i < (quarter + 1) * 1024; i += 256) {
    float d = dg[i];
    s += fmaxf(rm[i] + 0.5f - d, 0.f) + fmaxf(cm[i] + 0.5f - d, 0.f);
  }
  for (int o = 32; o > 0; o >>= 1) s += __shfl_xor(s, o);
  __shared__ float red[4];
  if ((t & 63) == 0) red[t >> 6] = s;
  __syncthreads();
  if (t == 0) atomicAdd(accum, red[0] + red[1] + red[2] + red[3]);
}

__global__ void cyc_lossB(const float* __restrict__ accum, float* __restrict__ out) {
  if (threadIdx.x == 0) out[0] = accum[0] * (1.f / (2.f * NN * 3.f));
}

// ---------------------------------------------------------------------------
static void process_term(const unsigned short* X, int term, unsigned short* Abuf,
                         unsigned short* Bbuf, float* arr, hipStream_t s) {
  float* base = arr + (size_t)term * 5 * NN;
  float* rs = base;
  float* cs = base + NN;
  float* rmax = base + 2 * NN;
  float* cmax = base + 3 * NN;
  float* dg = base + 4 * NN;
  cyc_abgen<<<8192, 256, 0, s>>>(X, rs, cs, Abuf, Bbuf);
  cyc_gemm<NN, true><<<256, 512, 0, s>>>(Abuf, Bbuf, nullptr, rmax, cmax, dg);
}

extern "C" void kernel_launch(void* const* d_in, const int* in_sizes, int n_in,
                              void* d_out, int out_size, void* d_ws, size_t ws_size,
                              hipStream_t stream) {
  (void)in_sizes; (void)n_in; (void)out_size; (void)ws_size;
  const float* f0 = (const float*)d_in[0];
  const float* f1 = (const float*)d_in[1];
  const float* f2 = (const float*)d_in[2];
  char* ws = (char*)d_ws;

  const size_t NF_ELEMS = (size_t)NN * DD;     // 4M shorts = 8 MB
  const size_t S_ELEMS = (size_t)NN * NN;      // 16M shorts = 32 MB
  unsigned short* NF0 = (unsigned short*)ws;
  unsigned short* NF1 = NF0 + NF_ELEMS;
  unsigned short* NF2 = NF1 + NF_ELEMS;
  unsigned short* SA = NF2 + NF_ELEMS; // S01
  unsigned short* SB = SA + S_ELEMS;   // S02
  unsigned short* SC = SB + S_ELEMS;   // S12
  unsigned short* TB = SC + S_ELEMS;   // scratch matrix
  unsigned short* AB = TB + S_ELEMS;   // A (rowsoftmax)
  unsigned short* BB = AB + S_ELEMS;   // Bc (colsoftmax)
  float* arr = (float*)(BB + S_ELEMS); // [6][5][4096] fp32 + accum
  float* accum = arr + 6 * 5 * NN;
  float* out = (float*)d_out;

#define TRS(k) (arr + (size_t)(k) * 5 * NN)
#define TCS(k) (arr + (size_t)(k) * 5 * NN + NN)

  cyc_zero<<<(6 * 5 * NN + 256 + 255) / 256, 256, 0, stream>>>(arr, 6 * 5 * NN + 256);
  cyc_norm<<<NN, 256, 0, stream>>>(f0, NF0);
  cyc_norm<<<NN, 256, 0, stream>>>(f1, NF1);
  cyc_norm<<<NN, 256, 0, stream>>>(f2, NF2);

  // pair similarity matrices (+ exp-sums for their cycle terms)
  cyc_gemm<DD, false><<<256, 512, 0, stream>>>(NF0, NF1, SA, TRS(0), TCS(0), nullptr);
  cyc_gemm<DD, false><<<256, 512, 0, stream>>>(NF0, NF2, SB, TRS(1), TCS(1), nullptr);
  cyc_gemm<DD, false><<<256, 512, 0, stream>>>(NF1, NF2, SC, TRS(2), TCS(2), nullptr);

  // pair terms
  process_term(SA, 0, AB, BB, arr, stream);
  process_term(SB, 1, AB, BB, arr, stream);
  process_term(SC, 2, AB, BB, arr, stream);

  // T1 = S02 @ S12^T = NT(SB, SC)
  cyc_gemm<NN, false><<<256, 512, 0, stream>>>(SB, SC, TB, TRS(3), TCS(3), nullptr);
  process_term(TB, 3, AB, BB, arr, stream);

  // T2 = S01 @ S12 = NT(SA, S12^T): transpose SC -> TB, output into SC slot
  cyc_trans<<<1024, 256, 0, stream>>>(SC, TB);
  cyc_gemm<NN, false><<<256, 512, 0, stream>>>(SA, TB, SC, TRS(4), TCS(4), nullptr);
  process_term(SC, 4, AB, BB, arr, stream);

  // T3 = S01^T @ S02 = NT(S01^T, S02^T): S10 -> TB, S20 -> AB, out into SA slot
  cyc_trans<<<1024, 256, 0, stream>>>(SA, TB);
  cyc_trans<<<1024, 256, 0, stream>>>(SB, AB);
  cyc_gemm<NN, false><<<256, 512, 0, stream>>>(TB, AB, SA, TRS(5), TCS(5), nullptr);
  process_term(SA, 5, AB, BB, arr, stream);

  cyc_lossA<<<24, 256, 0, stream>>>(arr, accum);
  cyc_lossB<<<1, 64, 0, stream>>>(accum, out);
#undef TRS
#undef TCS
}